// Round 7
// baseline (384.264 us; speedup 1.0000x reference)
//
#include <hip/hip_runtime.h>

#define N_NODES 50000
#define N_EDGES 500000
#define NUM_G   128
#define SCAN_NB 49              // ceil(50176/1024)
#define PN      (SCAN_NB * 1024) // 50176 padded node count
#define HIST_NCX 25             // edge chunks (500000 / 25 = 20000)
#define HIST_EC  20000
#define HIST_R   8192           // nodes per LDS range
#define HIST_NRY 7              // ceil(50000/8192)

typedef __attribute__((ext_vector_type(8))) short short8;
typedef __attribute__((ext_vector_type(4))) float f32x4;

__device__ __forceinline__ unsigned f2bf(float x) {
    unsigned u = __float_as_uint(x);
    return (u + 0x7FFFu + ((u >> 16) & 1u)) >> 16;   // RNE
}
__device__ __forceinline__ float bf2f(unsigned h) {
    return __uint_as_float(h << 16);
}

// ---------------- LDS partial histograms: deg (by src, weighted) + cnt (by dst) ----
__global__ void hist_kernel(const int* __restrict__ src, const int* __restrict__ dst,
                            const float* __restrict__ ea,
                            float* __restrict__ pdeg, int* __restrict__ pcnt) {
    __shared__ float ldeg[HIST_R];
    __shared__ int   lcnt[HIST_R];
    int x = blockIdx.x, y = blockIdx.y, tid = threadIdx.x;
    int base = y * HIST_R;
    for (int i = tid; i < HIST_R; i += 256) { ldeg[i] = 0.f; lcnt[i] = 0; }
    __syncthreads();
    int e0 = x * HIST_EC;
    for (int e = e0 + tid; e < e0 + HIST_EC; e += 256) {
        int s = src[e], d = dst[e];
        float a = ea[e];
        if ((unsigned)(s - base) < HIST_R) atomicAdd(&ldeg[s - base], a);
        if ((unsigned)(d - base) < HIST_R) atomicAdd(&lcnt[d - base], 1);
    }
    __syncthreads();
    for (int i = tid; i < HIST_R; i += 256) {
        int n = base + i;
        if (n < PN) {
            pdeg[(size_t)x * PN + n] = ldeg[i];
            pcnt[(size_t)x * PN + n] = lcnt[i];
        }
    }
}

// ---------------- reduce partials -> dinv, cnt; pcnt -> exclusive chunk-prefix -----
__global__ void reduce_kernel(float* __restrict__ pdeg, int* __restrict__ pcnt,
                              float* __restrict__ dinv, int* __restrict__ cnt) {
    int n = blockIdx.x * 256 + threadIdx.x;   // grid covers exactly PN
    float d = 0.f;
    int run = 0;
    for (int x = 0; x < HIST_NCX; ++x) {
        d += pdeg[(size_t)x * PN + n];
        int v = pcnt[(size_t)x * PN + n];
        pcnt[(size_t)x * PN + n] = run;       // exclusive prefix along chunks
        run += v;
    }
    if (n < N_NODES) {
        float r = 0.f;
        if (d > 0.f) {
            r = rsqrtf(d);
            r = r * (1.5f - 0.5f * d * r * r);   // Newton refine to ~fp32 exact
        }
        dinv[n] = r;
        cnt[n] = run;
    } else {
        cnt[n] = 0;                           // pad for scan
    }
}

// ---------------- 3-phase scan: cnt -> rowptr ----------------
__global__ void scan_partial_kernel(const int* __restrict__ cnt, int* __restrict__ partial) {
    int b = blockIdx.x, t = threadIdx.x;
    int4 v = reinterpret_cast<const int4*>(cnt)[b * 256 + t];
    int s = v.x + v.y + v.z + v.w;
    __shared__ int red[256];
    red[t] = s;
    __syncthreads();
    for (int off = 128; off > 0; off >>= 1) {
        if (t < off) red[t] += red[t + off];
        __syncthreads();
    }
    if (t == 0) partial[b] = red[0];
}

__global__ void scan_offsets_kernel(int* __restrict__ partial, int* __restrict__ rowptr,
                                    int nb, int n) {
    int t = threadIdx.x;  // single wave of 64
    int orig = (t < nb) ? partial[t] : 0;
    int v = orig;
    for (int off = 1; off < 64; off <<= 1) {
        int u = __shfl_up(v, off, 64);
        if (t >= off) v += u;
    }
    if (t < nb) partial[t] = v - orig;
    if (t == nb - 1) rowptr[n] = v;
}

__global__ void scan_final_kernel(const int* __restrict__ cnt, const int* __restrict__ partial,
                                  int* __restrict__ rowptr, int n) {
    int b = blockIdx.x, t = threadIdx.x;
    int4 v = reinterpret_cast<const int4*>(cnt)[b * 256 + t];
    int s = v.x + v.y + v.z + v.w;
    __shared__ int red[256];
    red[t] = s;
    __syncthreads();
    for (int off = 1; off < 256; off <<= 1) {
        int u = (t >= off) ? red[t - off] : 0;
        __syncthreads();
        red[t] += u;
        __syncthreads();
    }
    int excl = partial[b] + ((t == 0) ? 0 : red[t - 1]);
    int i0 = b * 1024 + t * 4;
    if (i0 < n)     rowptr[i0]     = excl;
    if (i0 + 1 < n) rowptr[i0 + 1] = excl + v.x;
    if (i0 + 2 < n) rowptr[i0 + 2] = excl + v.x + v.y;
    if (i0 + 3 < n) rowptr[i0 + 3] = excl + v.x + v.y + v.z;
}

// ---------------- deterministic CSR scatter (LDS cursors, no device atomics) -------
__global__ void scatter_kernel(const int* __restrict__ src, const int* __restrict__ dst,
                               const float* __restrict__ ea, const float* __restrict__ dinv,
                               const int* __restrict__ rowptr, const int* __restrict__ pcnt,
                               int* __restrict__ csr_src, float* __restrict__ csr_w) {
    __shared__ int cursor[HIST_R];
    int x = blockIdx.x, y = blockIdx.y, tid = threadIdx.x;
    int base = y * HIST_R;
    for (int i = tid; i < HIST_R; i += 256) {
        int n = base + i;
        cursor[i] = (n < N_NODES) ? (rowptr[n] + pcnt[(size_t)x * PN + n]) : 0;
    }
    __syncthreads();
    int e0 = x * HIST_EC;
    for (int e = e0 + tid; e < e0 + HIST_EC; e += 256) {
        int d = dst[e];
        if ((unsigned)(d - base) < HIST_R) {
            int s = src[e];
            float wv = -dinv[s] * ea[e] * dinv[d];
            int pos = atomicAdd(&cursor[d - base], 1);   // LDS atomic
            csr_src[pos] = s;
            csr_w[pos] = wv;
        }
    }
}

// ---------------- fp32 -> bf16 conversion ----------------
__global__ void conv_bf16_kernel(const float* __restrict__ x, unsigned short* __restrict__ o, int n4) {
    int t = blockIdx.x * blockDim.x + threadIdx.x;
    if (t >= n4) return;
    float4 v = reinterpret_cast<const float4*>(x)[t];
    ushort4 r;
    r.x = (unsigned short)f2bf(v.x);
    r.y = (unsigned short)f2bf(v.y);
    r.z = (unsigned short)f2bf(v.z);
    r.w = (unsigned short)f2bf(v.w);
    *reinterpret_cast<ushort4*>(o + (size_t)t * 4) = r;
}

// Build WcatT bf16 for all three layers in one kernel.
// WT[n][k], n in [0,3F): block 0 = W0 - W2, block 1 = W1, block 2 = W2.
__device__ __forceinline__ void wprep_one(const float* __restrict__ W, unsigned short* __restrict__ WT,
                                          int t, int FIN, int F) {
    int n = t / FIN, k = t - n * FIN;
    int sel = n / F, c = n - sel * F;
    float v;
    if (sel == 0) v = W[(size_t)k * F + c] - W[(size_t)2 * FIN * F + (size_t)k * F + c];
    else          v = W[(size_t)sel * FIN * F + (size_t)k * F + c];
    WT[t] = (unsigned short)f2bf(v);
}

__global__ void wprep_all_kernel(const float* __restrict__ W1, const float* __restrict__ W2,
                                 const float* __restrict__ W3,
                                 unsigned short* __restrict__ WT1, unsigned short* __restrict__ WT2,
                                 unsigned short* __restrict__ WT3) {
    int t = blockIdx.x * 256 + threadIdx.x;
    // sizes: 384*160 = 61440, 192*128 = 24576, 96*64 = 6144 (total 92160)
    if (t < 61440)      wprep_one(W1, WT1, t, 160, 128);
    else if (t < 86016) wprep_one(W2, WT2, t - 61440, 128, 64);
    else if (t < 92160) wprep_one(W3, WT3, t - 86016, 64, 32);
}

// ---------------- MFMA GEMM: [Y0|Y1|Y2] = Xb @ WcatT^T  (bf16 out) ----------------
// M-tile 64, grid (nrows/64, 3). Group g computes output matrix g.
// A fragments: direct global->reg. B tile in LDS with column-interleave perm so each
// lane's (b0,b1) accs are adjacent cols -> ushort2 pack -> full-line stores.
template<int FIN, int F>
__launch_bounds__(256)
__global__ void cheb_gemm(const unsigned short* __restrict__ Xb, const unsigned short* __restrict__ WT,
                          unsigned short* __restrict__ Y0, unsigned short* __restrict__ Y1,
                          unsigned short* __restrict__ Y2,
                          int nrows) {
    constexpr int KT = FIN / 32;
    constexpr int NT = F / 32;
    constexpr int SA = FIN + 8;
    constexpr int F8 = FIN / 8;
    __shared__ short Bs[32 * SA];

    int tid = threadIdx.x;
    int lane = tid & 63, w = tid >> 6;
    int m0 = blockIdx.x * 64;
    int g = blockIdx.y;
    unsigned short* Ys = (g == 0) ? Y0 : (g == 1) ? Y1 : Y2;

    int colb = lane & 15;
    int q8 = (lane >> 4) << 3;
    int rq = (lane >> 4) << 2;
    int arow = m0 + w * 16 + colb;
    bool rok = arow < nrows;

    short8 afr[KT];
    #pragma unroll
    for (int kt = 0; kt < KT; ++kt) {
        short8 z = {0, 0, 0, 0, 0, 0, 0, 0};
        afr[kt] = rok ? *reinterpret_cast<const short8*>(Xb + (size_t)arow * FIN + (kt << 5) + q8) : z;
    }

    for (int nt = 0; nt < NT; ++nt) {
        int n0 = (g * NT + nt) << 5;
        __syncthreads();
        for (int span = tid; span < 32 * F8; span += 256) {
            int r = span / F8, c8 = (span - r * F8) << 3;
            int pr = (r < 16) ? (r << 1) : (((r - 16) << 1) + 1);
            *reinterpret_cast<uint4*>(&Bs[r * SA + c8]) =
                *reinterpret_cast<const uint4*>(WT + (size_t)(n0 + pr) * FIN + c8);
        }
        __syncthreads();

        f32x4 acc0 = {0.f, 0.f, 0.f, 0.f}, acc1 = acc0;
        #pragma unroll
        for (int kt = 0; kt < KT; ++kt) {
            short8 b0 = *reinterpret_cast<const short8*>(&Bs[colb * SA + (kt << 5) + q8]);
            short8 b1 = *reinterpret_cast<const short8*>(&Bs[(colb + 16) * SA + (kt << 5) + q8]);
            acc0 = __builtin_amdgcn_mfma_f32_16x16x32_bf16(afr[kt], b0, acc0, 0, 0, 0);
            acc1 = __builtin_amdgcn_mfma_f32_16x16x32_bf16(afr[kt], b1, acc1, 0, 0, 0);
        }

        int lc = (nt << 5) + (colb << 1);
        #pragma unroll
        for (int r = 0; r < 4; ++r) {
            int orow = m0 + w * 16 + rq + r;
            if (orow < nrows) {
                unsigned pack = f2bf(acc0[r]) | (f2bf(acc1[r]) << 16);
                *reinterpret_cast<unsigned*>(Ys + (size_t)orow * F + lc) = pack;
            }
        }
    }
}

// ---------------- bf16 CSR gathers with fused epilogues ----------------
__device__ __forceinline__ void acc8(float* acc, uint4 p, float wv) {
    acc[0] += wv * bf2f(p.x & 0xFFFFu);
    acc[1] += wv * __uint_as_float(p.x & 0xFFFF0000u);
    acc[2] += wv * bf2f(p.y & 0xFFFFu);
    acc[3] += wv * __uint_as_float(p.y & 0xFFFF0000u);
    acc[4] += wv * bf2f(p.z & 0xFFFFu);
    acc[5] += wv * __uint_as_float(p.z & 0xFFFF0000u);
    acc[6] += wv * bf2f(p.w & 0xFFFFu);
    acc[7] += wv * __uint_as_float(p.w & 0xFFFF0000u);
}

__device__ __forceinline__ void expand8(uint4 p, float* o) {
    o[0] = bf2f(p.x & 0xFFFFu);
    o[1] = __uint_as_float(p.x & 0xFFFF0000u);
    o[2] = bf2f(p.y & 0xFFFFu);
    o[3] = __uint_as_float(p.y & 0xFFFF0000u);
    o[4] = bf2f(p.z & 0xFFFFu);
    o[5] = __uint_as_float(p.z & 0xFFFF0000u);
    o[6] = bf2f(p.w & 0xFFFFu);
    o[7] = __uint_as_float(p.w & 0xFFFF0000u);
}

// Z = P(Y2);  U = bf16(Y1 + 2Z)
__global__ void gather_z_kernel(const unsigned short* __restrict__ X, const int* __restrict__ csr_src,
                                const float* __restrict__ csr_w, const int* __restrict__ rowptr,
                                const unsigned short* __restrict__ Y1, unsigned short* __restrict__ U,
                                int n, int F) {
    int Fq8 = F >> 3;
    int t = blockIdx.x * blockDim.x + threadIdx.x;
    int d = t / Fq8;
    if (d >= n) return;
    int f8 = (t - d * Fq8) << 3;
    int beg = rowptr[d], end = rowptr[d + 1];
    float acc[8] = {0.f, 0.f, 0.f, 0.f, 0.f, 0.f, 0.f, 0.f};
    int i = beg;
    for (; i + 1 < end; i += 2) {
        int s0 = csr_src[i], s1 = csr_src[i + 1];
        float w0 = csr_w[i], w1 = csr_w[i + 1];
        uint4 p0 = *reinterpret_cast<const uint4*>(X + (size_t)s0 * F + f8);
        uint4 p1 = *reinterpret_cast<const uint4*>(X + (size_t)s1 * F + f8);
        acc8(acc, p0, w0);
        acc8(acc, p1, w1);
    }
    if (i < end) {
        uint4 p0 = *reinterpret_cast<const uint4*>(X + (size_t)csr_src[i] * F + f8);
        acc8(acc, p0, csr_w[i]);
    }
    float y[8];
    expand8(*reinterpret_cast<const uint4*>(Y1 + (size_t)d * F + f8), y);
    uint4 o;
    o.x = f2bf(y[0] + 2.f * acc[0]) | (f2bf(y[1] + 2.f * acc[1]) << 16);
    o.y = f2bf(y[2] + 2.f * acc[2]) | (f2bf(y[3] + 2.f * acc[3]) << 16);
    o.z = f2bf(y[4] + 2.f * acc[4]) | (f2bf(y[5] + 2.f * acc[5]) << 16);
    o.w = f2bf(y[6] + 2.f * acc[6]) | (f2bf(y[7] + 2.f * acc[7]) << 16);
    *reinterpret_cast<uint4*>(U + (size_t)d * F + f8) = o;
}

// V = P(U);  Xn = bf16(relu(Y0 + V + b))
__global__ void gather_v_kernel(const unsigned short* __restrict__ X, const int* __restrict__ csr_src,
                                const float* __restrict__ csr_w, const int* __restrict__ rowptr,
                                const unsigned short* __restrict__ Y0, const float* __restrict__ bias,
                                unsigned short* __restrict__ Xn, int n, int F) {
    int Fq8 = F >> 3;
    int t = blockIdx.x * blockDim.x + threadIdx.x;
    int d = t / Fq8;
    if (d >= n) return;
    int f8 = (t - d * Fq8) << 3;
    int beg = rowptr[d], end = rowptr[d + 1];
    float acc[8] = {0.f, 0.f, 0.f, 0.f, 0.f, 0.f, 0.f, 0.f};
    int i = beg;
    for (; i + 1 < end; i += 2) {
        int s0 = csr_src[i], s1 = csr_src[i + 1];
        float w0 = csr_w[i], w1 = csr_w[i + 1];
        uint4 p0 = *reinterpret_cast<const uint4*>(X + (size_t)s0 * F + f8);
        uint4 p1 = *reinterpret_cast<const uint4*>(X + (size_t)s1 * F + f8);
        acc8(acc, p0, w0);
        acc8(acc, p1, w1);
    }
    if (i < end) {
        uint4 p0 = *reinterpret_cast<const uint4*>(X + (size_t)csr_src[i] * F + f8);
        acc8(acc, p0, csr_w[i]);
    }
    float y[8];
    expand8(*reinterpret_cast<const uint4*>(Y0 + (size_t)d * F + f8), y);
    float4 ba = *reinterpret_cast<const float4*>(bias + f8);
    float4 bb = *reinterpret_cast<const float4*>(bias + f8 + 4);
    float v0 = fmaxf(y[0] + acc[0] + ba.x, 0.f);
    float v1 = fmaxf(y[1] + acc[1] + ba.y, 0.f);
    float v2 = fmaxf(y[2] + acc[2] + ba.z, 0.f);
    float v3 = fmaxf(y[3] + acc[3] + ba.w, 0.f);
    float v4 = fmaxf(y[4] + acc[4] + bb.x, 0.f);
    float v5 = fmaxf(y[5] + acc[5] + bb.y, 0.f);
    float v6 = fmaxf(y[6] + acc[6] + bb.z, 0.f);
    float v7 = fmaxf(y[7] + acc[7] + bb.w, 0.f);
    uint4 o;
    o.x = f2bf(v0) | (f2bf(v1) << 16);
    o.y = f2bf(v2) | (f2bf(v3) << 16);
    o.z = f2bf(v4) | (f2bf(v5) << 16);
    o.w = f2bf(v6) | (f2bf(v7) << 16);
    *reinterpret_cast<uint4*>(Xn + (size_t)d * F + f8) = o;
}

// ---------------- pooling + final linear ----------------
__device__ __forceinline__ int lower_bound_dev(const int* __restrict__ a, int n, int v) {
    int lo = 0, hi = n;
    while (lo < hi) {
        int mid = (lo + hi) >> 1;
        if (a[mid] < v) lo = mid + 1; else hi = mid;
    }
    return lo;
}

__global__ void pool_kernel(const unsigned short* __restrict__ H, const int* __restrict__ batch,
                            const float* __restrict__ Wl, const float* __restrict__ bl,
                            float* __restrict__ out, int n) {
    int g = blockIdx.x;
    int start = lower_bound_dev(batch, n, g);
    int end   = lower_bound_dev(batch, n, g + 1);
    int tid = threadIdx.x;
    int f = tid & 31;
    int sub = tid >> 5;
    float acc = 0.0f;
    for (int i = start + sub; i < end; i += 8)
        acc += bf2f((unsigned)H[(size_t)i * 32 + f]);
    __shared__ float red[256];
    red[tid] = acc;
    __syncthreads();
    if (tid < 128) red[tid] += red[tid + 128];
    __syncthreads();
    if (tid < 64) red[tid] += red[tid + 64];
    __syncthreads();
    if (tid < 32) red[tid] += red[tid + 32];
    __syncthreads();
    if (tid < 2) {
        int cnt = end - start;
        float inv = 1.0f / (float)(cnt > 0 ? cnt : 1);
        float o = bl[tid];
        for (int f2 = 0; f2 < 32; ++f2)
            o += red[f2] * inv * Wl[f2 * 2 + tid];
        out[g * 2 + tid] = o;
    }
}

extern "C" void kernel_launch(void* const* d_in, const int* in_sizes, int n_in,
                              void* d_out, int out_size, void* d_ws, size_t ws_size,
                              hipStream_t stream) {
    const float* x     = (const float*)d_in[0];
    const int*   ei    = (const int*)d_in[1];
    const float* ea    = (const float*)d_in[2];
    const int*   batch = (const int*)d_in[3];
    const float* W1 = (const float*)d_in[4];
    const float* b1 = (const float*)d_in[5];
    const float* W2 = (const float*)d_in[6];
    const float* b2 = (const float*)d_in[7];
    const float* W3 = (const float*)d_in[8];
    const float* b3 = (const float*)d_in[9];
    const float* Wl = (const float*)d_in[10];
    const float* bl = (const float*)d_in[11];
    float* out = (float*)d_out;
    char* ws = (char*)d_ws;

    const int* src = ei;
    const int* dst = ei + N_EDGES;

    size_t off = 0;
    auto alloc = [&](size_t bytes) { char* p = ws + off; off += (bytes + 255) & ~(size_t)255; return p; };
    float* pdeg    = (float*)alloc((size_t)HIST_NCX * PN * 4);
    int*   pcnt    = (int*)  alloc((size_t)HIST_NCX * PN * 4);
    float* dinv    = (float*)alloc(N_NODES * 4);
    int*   cnt     = (int*)  alloc((size_t)PN * 4);
    int*   partial = (int*)  alloc(SCAN_NB * 4);
    int*   rowptr  = (int*)  alloc((N_NODES + 1) * 4);
    int*   csr_src = (int*)  alloc((size_t)N_EDGES * 4);
    float* csr_w   = (float*)alloc((size_t)N_EDGES * 4);
    unsigned short* Xb  = (unsigned short*)alloc((size_t)N_NODES * 160 * 2);
    unsigned short* Y0  = (unsigned short*)alloc((size_t)N_NODES * 128 * 2);
    unsigned short* Y1  = (unsigned short*)alloc((size_t)N_NODES * 128 * 2);
    unsigned short* Y2  = (unsigned short*)alloc((size_t)N_NODES * 128 * 2);
    unsigned short* U   = (unsigned short*)alloc((size_t)N_NODES * 128 * 2);
    unsigned short* WT1 = (unsigned short*)alloc((size_t)384 * 160 * 2);
    unsigned short* WT2 = (unsigned short*)alloc((size_t)192 * 128 * 2);
    unsigned short* WT3 = (unsigned short*)alloc((size_t)96 * 64 * 2);

    const int BT = 256;
    dim3 hgrid(HIST_NCX, HIST_NRY);

    // preprocessing: zero device-scope atomics
    hist_kernel<<<hgrid, BT, 0, stream>>>(src, dst, ea, pdeg, pcnt);
    reduce_kernel<<<PN / BT, BT, 0, stream>>>(pdeg, pcnt, dinv, cnt);
    scan_partial_kernel<<<SCAN_NB, BT, 0, stream>>>(cnt, partial);
    scan_offsets_kernel<<<1, 64, 0, stream>>>(partial, rowptr, SCAN_NB, N_NODES);
    scan_final_kernel<<<SCAN_NB, BT, 0, stream>>>(cnt, partial, rowptr, N_NODES);
    scatter_kernel<<<hgrid, BT, 0, stream>>>(src, dst, ea, dinv, rowptr, pcnt, csr_src, csr_w);

    int n4 = N_NODES * 160 / 4;
    conv_bf16_kernel<<<(n4 + BT - 1) / BT, BT, 0, stream>>>(x, Xb, n4);
    wprep_all_kernel<<<360, BT, 0, stream>>>(W1, W2, W3, WT1, WT2, WT3);

    dim3 ggrid((N_NODES + 63) / 64, 3);
    auto gathers = [&](const float* bias, int F) {
        int gth = N_NODES * (F / 8);
        int ggr = (gth + BT - 1) / BT;
        gather_z_kernel<<<ggr, BT, 0, stream>>>(Y2, csr_src, csr_w, rowptr, Y1, U, N_NODES, F);
        gather_v_kernel<<<ggr, BT, 0, stream>>>(U, csr_src, csr_w, rowptr, Y0, bias, Xb, N_NODES, F);
    };

    cheb_gemm<160, 128><<<ggrid, BT, 0, stream>>>(Xb, WT1, Y0, Y1, Y2, N_NODES);
    gathers(b1, 128);
    cheb_gemm<128, 64><<<ggrid, BT, 0, stream>>>(Xb, WT2, Y0, Y1, Y2, N_NODES);
    gathers(b2, 64);
    cheb_gemm<64, 32><<<ggrid, BT, 0, stream>>>(Xb, WT3, Y0, Y1, Y2, N_NODES);
    gathers(b3, 32);

    pool_kernel<<<NUM_G, BT, 0, stream>>>(Xb, batch, Wl, bl, out, N_NODES);
}

// Round 8
// 336.886 us; speedup vs baseline: 1.1406x; 1.1406x over previous
//
#include <hip/hip_runtime.h>

#define N_NODES 50000
#define N_EDGES 500000
#define NUM_G   128
#define SCAN_NB 49               // ceil(50176/1024)
#define PN      (SCAN_NB * 1024) // 50176 padded node count
#define HIST_NCX 64              // edge chunks
#define HIST_EC  7813            // 64*7813 >= 500000
#define HIST_R   16384           // nodes per LDS range (64 KB)
#define HIST_NRY 4               // ceil(50176/16384)

typedef __attribute__((ext_vector_type(8))) short short8;
typedef __attribute__((ext_vector_type(4))) float f32x4;

__device__ __forceinline__ unsigned f2bf(float x) {
    unsigned u = __float_as_uint(x);
    return (u + 0x7FFFu + ((u >> 16) & 1u)) >> 16;   // RNE
}
__device__ __forceinline__ float bf2f(unsigned h) {
    return __uint_as_float(h << 16);
}

// ---------------- LDS partial histograms ----------------
// grid (64, 8): y<4 -> weighted deg by src ; y>=4 -> cnt by dst (range y-4)
__global__ void hist_kernel(const int* __restrict__ src, const int* __restrict__ dst,
                            const float* __restrict__ ea,
                            float* __restrict__ pdeg, int* __restrict__ pcnt) {
    __shared__ unsigned lh[HIST_R];
    int x = blockIdx.x, y = blockIdx.y, tid = threadIdx.x;
    bool isdeg = y < HIST_NRY;
    int base = (isdeg ? y : y - HIST_NRY) * HIST_R;
    for (int i = tid; i < HIST_R; i += 256) lh[i] = 0u;
    __syncthreads();
    int e0 = x * HIST_EC, e1 = min(e0 + HIST_EC, N_EDGES);
    if (isdeg) {
        for (int e = e0 + tid; e < e1; e += 256) {
            int s = src[e];
            if ((unsigned)(s - base) < HIST_R) atomicAdd((float*)&lh[s - base], ea[e]);
        }
    } else {
        for (int e = e0 + tid; e < e1; e += 256) {
            int d = dst[e];
            if ((unsigned)(d - base) < HIST_R) atomicAdd((int*)&lh[d - base], 1);
        }
    }
    __syncthreads();
    if (isdeg) {
        for (int i = tid; i < HIST_R; i += 256) {
            int n = base + i;
            if (n < PN) pdeg[(size_t)x * PN + n] = ((float*)lh)[i];
        }
    } else {
        for (int i = tid; i < HIST_R; i += 256) {
            int n = base + i;
            if (n < PN) pcnt[(size_t)x * PN + n] = ((int*)lh)[i];
        }
    }
}

// ---------------- reduce partials -> dinv, cnt; pcnt -> exclusive chunk-prefix -----
__global__ void reduce_kernel(const float* __restrict__ pdeg, int* __restrict__ pcnt,
                              float* __restrict__ dinv, int* __restrict__ cnt) {
    int n = blockIdx.x * 256 + threadIdx.x;   // grid covers exactly PN
    float d = 0.f;
    int run = 0;
    for (int x = 0; x < HIST_NCX; ++x) {
        d += pdeg[(size_t)x * PN + n];
        int v = pcnt[(size_t)x * PN + n];
        pcnt[(size_t)x * PN + n] = run;       // exclusive prefix along chunks
        run += v;
    }
    if (n < N_NODES) {
        float r = 0.f;
        if (d > 0.f) {
            r = rsqrtf(d);
            r = r * (1.5f - 0.5f * d * r * r);   // Newton refine to ~fp32 exact
        }
        dinv[n] = r;
        cnt[n] = run;
    } else {
        cnt[n] = 0;                           // pad for scan
    }
}

// ---------------- 3-phase scan: cnt -> rowptr ----------------
__global__ void scan_partial_kernel(const int* __restrict__ cnt, int* __restrict__ partial) {
    int b = blockIdx.x, t = threadIdx.x;
    int4 v = reinterpret_cast<const int4*>(cnt)[b * 256 + t];
    int s = v.x + v.y + v.z + v.w;
    __shared__ int red[256];
    red[t] = s;
    __syncthreads();
    for (int off = 128; off > 0; off >>= 1) {
        if (t < off) red[t] += red[t + off];
        __syncthreads();
    }
    if (t == 0) partial[b] = red[0];
}

__global__ void scan_offsets_kernel(int* __restrict__ partial, int* __restrict__ rowptr,
                                    int nb, int n) {
    int t = threadIdx.x;  // single wave of 64
    int orig = (t < nb) ? partial[t] : 0;
    int v = orig;
    for (int off = 1; off < 64; off <<= 1) {
        int u = __shfl_up(v, off, 64);
        if (t >= off) v += u;
    }
    if (t < nb) partial[t] = v - orig;
    if (t == nb - 1) rowptr[n] = v;
}

__global__ void scan_final_kernel(const int* __restrict__ cnt, const int* __restrict__ partial,
                                  int* __restrict__ rowptr, int n) {
    int b = blockIdx.x, t = threadIdx.x;
    int4 v = reinterpret_cast<const int4*>(cnt)[b * 256 + t];
    int s = v.x + v.y + v.z + v.w;
    __shared__ int red[256];
    red[t] = s;
    __syncthreads();
    for (int off = 1; off < 256; off <<= 1) {
        int u = (t >= off) ? red[t - off] : 0;
        __syncthreads();
        red[t] += u;
        __syncthreads();
    }
    int excl = partial[b] + ((t == 0) ? 0 : red[t - 1]);
    int i0 = b * 1024 + t * 4;
    if (i0 < n)     rowptr[i0]     = excl;
    if (i0 + 1 < n) rowptr[i0 + 1] = excl + v.x;
    if (i0 + 2 < n) rowptr[i0 + 2] = excl + v.x + v.y;
    if (i0 + 3 < n) rowptr[i0 + 3] = excl + v.x + v.y + v.z;
}

// ---------------- deterministic CSR scatter (LDS cursors, interleaved int2) -------
// csr[i] = (src, ea)  -- dinv folded out of edge weights entirely.
__global__ void scatter_kernel(const int* __restrict__ src, const int* __restrict__ dst,
                               const float* __restrict__ ea,
                               const int* __restrict__ rowptr, const int* __restrict__ pcnt,
                               int2* __restrict__ csr) {
    __shared__ int cursor[HIST_R];
    int x = blockIdx.x, y = blockIdx.y, tid = threadIdx.x;
    int base = y * HIST_R;
    for (int i = tid; i < HIST_R; i += 256) {
        int n = base + i;
        cursor[i] = (n < N_NODES) ? (rowptr[n] + pcnt[(size_t)x * PN + n]) : 0;
    }
    __syncthreads();
    int e0 = x * HIST_EC, e1 = min(e0 + HIST_EC, N_EDGES);
    for (int e = e0 + tid; e < e1; e += 256) {
        int d = dst[e];
        if ((unsigned)(d - base) < HIST_R) {
            int pos = atomicAdd(&cursor[d - base], 1);   // LDS atomic
            int2 ew;
            ew.x = src[e];
            ew.y = __float_as_int(ea[e]);
            csr[pos] = ew;
        }
    }
}

// ---------------- fp32 -> bf16 conversion ----------------
__global__ void conv_bf16_kernel(const float* __restrict__ x, unsigned short* __restrict__ o, int n4) {
    int t = blockIdx.x * blockDim.x + threadIdx.x;
    if (t >= n4) return;
    float4 v = reinterpret_cast<const float4*>(x)[t];
    ushort4 r;
    r.x = (unsigned short)f2bf(v.x);
    r.y = (unsigned short)f2bf(v.y);
    r.z = (unsigned short)f2bf(v.z);
    r.w = (unsigned short)f2bf(v.w);
    *reinterpret_cast<ushort4*>(o + (size_t)t * 4) = r;
}

// Build WcatT bf16 for all three layers in one kernel.
__device__ __forceinline__ void wprep_one(const float* __restrict__ W, unsigned short* __restrict__ WT,
                                          int t, int FIN, int F) {
    int n = t / FIN, k = t - n * FIN;
    int sel = n / F, c = n - sel * F;
    float v;
    if (sel == 0) v = W[(size_t)k * F + c] - W[(size_t)2 * FIN * F + (size_t)k * F + c];
    else          v = W[(size_t)sel * FIN * F + (size_t)k * F + c];
    WT[t] = (unsigned short)f2bf(v);
}

__global__ void wprep_all_kernel(const float* __restrict__ W1, const float* __restrict__ W2,
                                 const float* __restrict__ W3,
                                 unsigned short* __restrict__ WT1, unsigned short* __restrict__ WT2,
                                 unsigned short* __restrict__ WT3) {
    int t = blockIdx.x * 256 + threadIdx.x;
    if (t < 61440)      wprep_one(W1, WT1, t, 160, 128);
    else if (t < 86016) wprep_one(W2, WT2, t - 61440, 128, 64);
    else if (t < 92160) wprep_one(W3, WT3, t - 86016, 64, 32);
}

// ---------------- MFMA GEMM: [Y0|Y1|Y2'] = Xb @ WcatT^T  (bf16 out) ---------------
// Group 2 output rows pre-scaled by dinv (Y2' = dinv .* T0 W2) for the folded gather.
template<int FIN, int F>
__launch_bounds__(256)
__global__ void cheb_gemm(const unsigned short* __restrict__ Xb, const unsigned short* __restrict__ WT,
                          const float* __restrict__ dinv,
                          unsigned short* __restrict__ Y0, unsigned short* __restrict__ Y1,
                          unsigned short* __restrict__ Y2,
                          int nrows) {
    constexpr int KT = FIN / 32;
    constexpr int NT = F / 32;
    constexpr int SA = FIN + 8;
    constexpr int F8 = FIN / 8;
    __shared__ short Bs[32 * SA];

    int tid = threadIdx.x;
    int lane = tid & 63, w = tid >> 6;
    int m0 = blockIdx.x * 64;
    int g = blockIdx.y;
    unsigned short* Ys = (g == 0) ? Y0 : (g == 1) ? Y1 : Y2;

    int colb = lane & 15;
    int q8 = (lane >> 4) << 3;
    int rq = (lane >> 4) << 2;
    int arow = m0 + w * 16 + colb;
    bool rok = arow < nrows;

    short8 afr[KT];
    #pragma unroll
    for (int kt = 0; kt < KT; ++kt) {
        short8 z = {0, 0, 0, 0, 0, 0, 0, 0};
        afr[kt] = rok ? *reinterpret_cast<const short8*>(Xb + (size_t)arow * FIN + (kt << 5) + q8) : z;
    }

    for (int nt = 0; nt < NT; ++nt) {
        int n0 = (g * NT + nt) << 5;
        __syncthreads();
        for (int span = tid; span < 32 * F8; span += 256) {
            int r = span / F8, c8 = (span - r * F8) << 3;
            int pr = (r < 16) ? (r << 1) : (((r - 16) << 1) + 1);
            *reinterpret_cast<uint4*>(&Bs[r * SA + c8]) =
                *reinterpret_cast<const uint4*>(WT + (size_t)(n0 + pr) * FIN + c8);
        }
        __syncthreads();

        f32x4 acc0 = {0.f, 0.f, 0.f, 0.f}, acc1 = acc0;
        #pragma unroll
        for (int kt = 0; kt < KT; ++kt) {
            short8 b0 = *reinterpret_cast<const short8*>(&Bs[colb * SA + (kt << 5) + q8]);
            short8 b1 = *reinterpret_cast<const short8*>(&Bs[(colb + 16) * SA + (kt << 5) + q8]);
            acc0 = __builtin_amdgcn_mfma_f32_16x16x32_bf16(afr[kt], b0, acc0, 0, 0, 0);
            acc1 = __builtin_amdgcn_mfma_f32_16x16x32_bf16(afr[kt], b1, acc1, 0, 0, 0);
        }

        int lc = (nt << 5) + (colb << 1);
        #pragma unroll
        for (int r = 0; r < 4; ++r) {
            int orow = m0 + w * 16 + rq + r;
            if (orow < nrows) {
                float sc = (g == 2) ? dinv[orow] : 1.0f;
                unsigned pack = f2bf(acc0[r] * sc) | (f2bf(acc1[r] * sc) << 16);
                *reinterpret_cast<unsigned*>(Ys + (size_t)orow * F + lc) = pack;
            }
        }
    }
}

// ---------------- bf16 CSR gathers with fused epilogues (dinv-folded) ----------------
__device__ __forceinline__ void acc8(float* acc, uint4 p, float wv) {
    acc[0] += wv * bf2f(p.x & 0xFFFFu);
    acc[1] += wv * __uint_as_float(p.x & 0xFFFF0000u);
    acc[2] += wv * bf2f(p.y & 0xFFFFu);
    acc[3] += wv * __uint_as_float(p.y & 0xFFFF0000u);
    acc[4] += wv * bf2f(p.z & 0xFFFFu);
    acc[5] += wv * __uint_as_float(p.z & 0xFFFF0000u);
    acc[6] += wv * bf2f(p.w & 0xFFFFu);
    acc[7] += wv * __uint_as_float(p.w & 0xFFFF0000u);
}

__device__ __forceinline__ void expand8(uint4 p, float* o) {
    o[0] = bf2f(p.x & 0xFFFFu);
    o[1] = __uint_as_float(p.x & 0xFFFF0000u);
    o[2] = bf2f(p.y & 0xFFFFu);
    o[3] = __uint_as_float(p.y & 0xFFFF0000u);
    o[4] = bf2f(p.z & 0xFFFFu);
    o[5] = __uint_as_float(p.z & 0xFFFF0000u);
    o[6] = bf2f(p.w & 0xFFFFu);
    o[7] = __uint_as_float(p.w & 0xFFFF0000u);
}

// t = A-gather(Y2');  U' = dinv .* (Y1 - 2*dinv*t)
__global__ void gather_z_kernel(const unsigned short* __restrict__ X, const int2* __restrict__ csr,
                                const int* __restrict__ rowptr, const float* __restrict__ dinv,
                                const unsigned short* __restrict__ Y1, unsigned short* __restrict__ U,
                                int n, int F) {
    int Fq8 = F >> 3;
    int t = blockIdx.x * blockDim.x + threadIdx.x;
    int d = t / Fq8;
    if (d >= n) return;
    int f8 = (t - d * Fq8) << 3;
    int beg = rowptr[d], end = rowptr[d + 1];
    float acc[8] = {0.f, 0.f, 0.f, 0.f, 0.f, 0.f, 0.f, 0.f};
    int i = beg;
    for (; i + 1 < end; i += 2) {
        int2 e0 = csr[i], e1 = csr[i + 1];
        uint4 p0 = *reinterpret_cast<const uint4*>(X + (size_t)e0.x * F + f8);
        uint4 p1 = *reinterpret_cast<const uint4*>(X + (size_t)e1.x * F + f8);
        acc8(acc, p0, __int_as_float(e0.y));
        acc8(acc, p1, __int_as_float(e1.y));
    }
    if (i < end) {
        int2 e0 = csr[i];
        uint4 p0 = *reinterpret_cast<const uint4*>(X + (size_t)e0.x * F + f8);
        acc8(acc, p0, __int_as_float(e0.y));
    }
    float y[8];
    expand8(*reinterpret_cast<const uint4*>(Y1 + (size_t)d * F + f8), y);
    float dv = dinv[d];
    float dv2 = 2.f * dv;
    uint4 o;
    o.x = f2bf(dv * (y[0] - dv2 * acc[0])) | (f2bf(dv * (y[1] - dv2 * acc[1])) << 16);
    o.y = f2bf(dv * (y[2] - dv2 * acc[2])) | (f2bf(dv * (y[3] - dv2 * acc[3])) << 16);
    o.z = f2bf(dv * (y[4] - dv2 * acc[4])) | (f2bf(dv * (y[5] - dv2 * acc[5])) << 16);
    o.w = f2bf(dv * (y[6] - dv2 * acc[6])) | (f2bf(dv * (y[7] - dv2 * acc[7])) << 16);
    *reinterpret_cast<uint4*>(U + (size_t)d * F + f8) = o;
}

// t = A-gather(U');  Xn = bf16(relu(Y0 - dinv*t + b))
__global__ void gather_v_kernel(const unsigned short* __restrict__ X, const int2* __restrict__ csr,
                                const int* __restrict__ rowptr, const float* __restrict__ dinv,
                                const unsigned short* __restrict__ Y0, const float* __restrict__ bias,
                                unsigned short* __restrict__ Xn, int n, int F) {
    int Fq8 = F >> 3;
    int t = blockIdx.x * blockDim.x + threadIdx.x;
    int d = t / Fq8;
    if (d >= n) return;
    int f8 = (t - d * Fq8) << 3;
    int beg = rowptr[d], end = rowptr[d + 1];
    float acc[8] = {0.f, 0.f, 0.f, 0.f, 0.f, 0.f, 0.f, 0.f};
    int i = beg;
    for (; i + 1 < end; i += 2) {
        int2 e0 = csr[i], e1 = csr[i + 1];
        uint4 p0 = *reinterpret_cast<const uint4*>(X + (size_t)e0.x * F + f8);
        uint4 p1 = *reinterpret_cast<const uint4*>(X + (size_t)e1.x * F + f8);
        acc8(acc, p0, __int_as_float(e0.y));
        acc8(acc, p1, __int_as_float(e1.y));
    }
    if (i < end) {
        int2 e0 = csr[i];
        uint4 p0 = *reinterpret_cast<const uint4*>(X + (size_t)e0.x * F + f8);
        acc8(acc, p0, __int_as_float(e0.y));
    }
    float y[8];
    expand8(*reinterpret_cast<const uint4*>(Y0 + (size_t)d * F + f8), y);
    float4 ba = *reinterpret_cast<const float4*>(bias + f8);
    float4 bb = *reinterpret_cast<const float4*>(bias + f8 + 4);
    float dv = dinv[d];
    float v0 = fmaxf(y[0] - dv * acc[0] + ba.x, 0.f);
    float v1 = fmaxf(y[1] - dv * acc[1] + ba.y, 0.f);
    float v2 = fmaxf(y[2] - dv * acc[2] + ba.z, 0.f);
    float v3 = fmaxf(y[3] - dv * acc[3] + ba.w, 0.f);
    float v4 = fmaxf(y[4] - dv * acc[4] + bb.x, 0.f);
    float v5 = fmaxf(y[5] - dv * acc[5] + bb.y, 0.f);
    float v6 = fmaxf(y[6] - dv * acc[6] + bb.z, 0.f);
    float v7 = fmaxf(y[7] - dv * acc[7] + bb.w, 0.f);
    uint4 o;
    o.x = f2bf(v0) | (f2bf(v1) << 16);
    o.y = f2bf(v2) | (f2bf(v3) << 16);
    o.z = f2bf(v4) | (f2bf(v5) << 16);
    o.w = f2bf(v6) | (f2bf(v7) << 16);
    *reinterpret_cast<uint4*>(Xn + (size_t)d * F + f8) = o;
}

// ---------------- pooling + final linear ----------------
__device__ __forceinline__ int lower_bound_dev(const int* __restrict__ a, int n, int v) {
    int lo = 0, hi = n;
    while (lo < hi) {
        int mid = (lo + hi) >> 1;
        if (a[mid] < v) lo = mid + 1; else hi = mid;
    }
    return lo;
}

__global__ void pool_kernel(const unsigned short* __restrict__ H, const int* __restrict__ batch,
                            const float* __restrict__ Wl, const float* __restrict__ bl,
                            float* __restrict__ out, int n) {
    int g = blockIdx.x;
    int start = lower_bound_dev(batch, n, g);
    int end   = lower_bound_dev(batch, n, g + 1);
    int tid = threadIdx.x;
    int f = tid & 31;
    int sub = tid >> 5;
    float acc = 0.0f;
    for (int i = start + sub; i < end; i += 8)
        acc += bf2f((unsigned)H[(size_t)i * 32 + f]);
    __shared__ float red[256];
    red[tid] = acc;
    __syncthreads();
    if (tid < 128) red[tid] += red[tid + 128];
    __syncthreads();
    if (tid < 64) red[tid] += red[tid + 64];
    __syncthreads();
    if (tid < 32) red[tid] += red[tid + 32];
    __syncthreads();
    if (tid < 2) {
        int cnt = end - start;
        float inv = 1.0f / (float)(cnt > 0 ? cnt : 1);
        float o = bl[tid];
        for (int f2 = 0; f2 < 32; ++f2)
            o += red[f2] * inv * Wl[f2 * 2 + tid];
        out[g * 2 + tid] = o;
    }
}

extern "C" void kernel_launch(void* const* d_in, const int* in_sizes, int n_in,
                              void* d_out, int out_size, void* d_ws, size_t ws_size,
                              hipStream_t stream) {
    const float* x     = (const float*)d_in[0];
    const int*   ei    = (const int*)d_in[1];
    const float* ea    = (const float*)d_in[2];
    const int*   batch = (const int*)d_in[3];
    const float* W1 = (const float*)d_in[4];
    const float* b1 = (const float*)d_in[5];
    const float* W2 = (const float*)d_in[6];
    const float* b2 = (const float*)d_in[7];
    const float* W3 = (const float*)d_in[8];
    const float* b3 = (const float*)d_in[9];
    const float* Wl = (const float*)d_in[10];
    const float* bl = (const float*)d_in[11];
    float* out = (float*)d_out;
    char* ws = (char*)d_ws;

    const int* src = ei;
    const int* dst = ei + N_EDGES;

    size_t off = 0;
    auto alloc = [&](size_t bytes) { char* p = ws + off; off += (bytes + 255) & ~(size_t)255; return p; };
    float* pdeg    = (float*)alloc((size_t)HIST_NCX * PN * 4);
    int*   pcnt    = (int*)  alloc((size_t)HIST_NCX * PN * 4);
    float* dinv    = (float*)alloc(N_NODES * 4);
    int*   cnt     = (int*)  alloc((size_t)PN * 4);
    int*   partial = (int*)  alloc(SCAN_NB * 4);
    int*   rowptr  = (int*)  alloc((N_NODES + 1) * 4);
    int2*  csr     = (int2*) alloc((size_t)N_EDGES * 8);
    unsigned short* Xb  = (unsigned short*)alloc((size_t)N_NODES * 160 * 2);
    unsigned short* Y0  = (unsigned short*)alloc((size_t)N_NODES * 128 * 2);
    unsigned short* Y1  = (unsigned short*)alloc((size_t)N_NODES * 128 * 2);
    unsigned short* Y2  = (unsigned short*)alloc((size_t)N_NODES * 128 * 2);
    unsigned short* U   = (unsigned short*)alloc((size_t)N_NODES * 128 * 2);
    unsigned short* WT1 = (unsigned short*)alloc((size_t)384 * 160 * 2);
    unsigned short* WT2 = (unsigned short*)alloc((size_t)192 * 128 * 2);
    unsigned short* WT3 = (unsigned short*)alloc((size_t)96 * 64 * 2);

    const int BT = 256;

    // preprocessing: zero device-scope atomics, full occupancy
    hist_kernel<<<dim3(HIST_NCX, 2 * HIST_NRY), BT, 0, stream>>>(src, dst, ea, pdeg, pcnt);
    reduce_kernel<<<PN / BT, BT, 0, stream>>>(pdeg, pcnt, dinv, cnt);
    scan_partial_kernel<<<SCAN_NB, BT, 0, stream>>>(cnt, partial);
    scan_offsets_kernel<<<1, 64, 0, stream>>>(partial, rowptr, SCAN_NB, N_NODES);
    scan_final_kernel<<<SCAN_NB, BT, 0, stream>>>(cnt, partial, rowptr, N_NODES);
    scatter_kernel<<<dim3(HIST_NCX, HIST_NRY), BT, 0, stream>>>(src, dst, ea, rowptr, pcnt, csr);

    int n4 = N_NODES * 160 / 4;
    conv_bf16_kernel<<<(n4 + BT - 1) / BT, BT, 0, stream>>>(x, Xb, n4);
    wprep_all_kernel<<<360, BT, 0, stream>>>(W1, W2, W3, WT1, WT2, WT3);

    dim3 ggrid((N_NODES + 63) / 64, 3);
    auto gathers = [&](const float* bias, int F) {
        int gth = N_NODES * (F / 8);
        int ggr = (gth + BT - 1) / BT;
        gather_z_kernel<<<ggr, BT, 0, stream>>>(Y2, csr, rowptr, dinv, Y1, U, N_NODES, F);
        gather_v_kernel<<<ggr, BT, 0, stream>>>(U, csr, rowptr, dinv, Y0, bias, Xb, N_NODES, F);
    };

    cheb_gemm<160, 128><<<ggrid, BT, 0, stream>>>(Xb, WT1, dinv, Y0, Y1, Y2, N_NODES);
    gathers(b1, 128);
    cheb_gemm<128, 64><<<ggrid, BT, 0, stream>>>(Xb, WT2, dinv, Y0, Y1, Y2, N_NODES);
    gathers(b2, 64);
    cheb_gemm<64, 32><<<ggrid, BT, 0, stream>>>(Xb, WT3, dinv, Y0, Y1, Y2, N_NODES);
    gathers(b3, 32);

    pool_kernel<<<NUM_G, BT, 0, stream>>>(Xb, batch, Wl, bl, out, N_NODES);
}